// Round 5
// baseline (102.930 us; speedup 1.0000x reference)
//
#include <hip/hip_runtime.h>
#include <math.h>

#define KS 21
#define K2 441
#define NB 8
#define PPI 4096
#define NPIX 65536
#define STR 72                     // LDS activation row stride (u16), 16B-aligned rows
#define XW 276

typedef unsigned short u16;
typedef unsigned int u32;
typedef short short8v __attribute__((ext_vector_type(8)));
typedef float f32x4 __attribute__((ext_vector_type(4)));
typedef float f32x16 __attribute__((ext_vector_type(16)));

// ws layout (u16 units): layer frags 17*4096 | wout frags 28672 | bout 448 f32
#define WOUT_OFF 69632
#define BOUT_BYTE 196608

__device__ __forceinline__ u16 f2bf(float x)
{
    union { float f; u32 u; } c; c.f = x;
    u32 r = c.u + 0x7FFF + ((c.u >> 16) & 1);
    return (u16)(r >> 16);
}
__device__ __forceinline__ float bflo(u32 w)
{ union { u32 u; float f; } c; c.u = w << 16; return c.f; }
__device__ __forceinline__ float bfhi(u32 w)
{ union { u32 u; float f; } c; c.u = w & 0xffff0000u; return c.f; }
__device__ __forceinline__ float u16f(u16 h)
{ union { u32 u; float f; } c; c.u = ((u32)h) << 16; return c.f; }

// ---------------------------------------------------------------- prep ----
// Layer weights: 16x16x32 B-frag layout (n=lane&15, k=(lane>>4)*8+j, kk*32).
// w_out: 32x32x16 A-frag layout (m=tap=lane&31, k=kk*16+(lane>>5)*8+j),
//   14 tap-tiles x 4 kk. Padded taps (>=441) -> weight 0, bias -100.
__global__ void prep_kernel(const float* __restrict__ w_in,
                            const float* __restrict__ rw1,
                            const float* __restrict__ rw2,
                            const float* __restrict__ w_out,
                            const float* __restrict__ b_out,
                            u16* __restrict__ wsu, float* __restrict__ bout)
{
    int idx = blockIdx.x * 256 + threadIdx.x;
    if (idx < 69632) {
        int u = idx & 4095;
        int j = u & 7, lane = (u >> 3) & 63, frag = (u >> 9) & 7;
        int kk = frag >> 2, nt = frag & 3, layer = idx >> 12;
        int i = kk * 32 + (lane >> 4) * 8 + j;      // K (input ch)
        int o = nt * 16 + (lane & 15);              // N (output ch)
        const float* src;
        if (layer == 0) src = w_in;
        else if (layer & 1) src = rw1 + ((layer - 1) >> 1) * 4096;
        else src = rw2 + ((layer - 2) >> 1) * 4096;
        wsu[idx] = f2bf(src[o * 64 + i]);
    } else if (idx < 69632 + 28672) {
        int u = idx - 69632;
        int j = u & 7, lane = (u >> 3) & 63, t6 = u >> 9;   // 0..55
        int t = t6 % 14, kk = t6 / 14;
        int tap = t * 32 + (lane & 31);
        int i = kk * 16 + (lane >> 5) * 8 + j;
        wsu[idx] = f2bf((tap < K2) ? w_out[tap * 64 + i] : 0.f);
    } else if (idx < 69632 + 28672 + 448) {
        int tap = idx - (69632 + 28672);
        bout[tap] = (tap < K2) ? b_out[tap] : -100.f;
    }
}

// --------------------------------------------------------------- fused ----
__device__ __forceinline__ int reflect256(int v)
{
    v = (v < 0) ? -v : v;
    return (v > 255) ? (510 - v) : v;
}

// Layer step, single in-place buffer (wave-private rows; reads complete
// before writes issue due to wave-lockstep program order).
template <int MODE>
__device__ __forceinline__ void do_layer(u16* hb, const u16* __restrict__ wb,
                                         const float* __restrict__ bias,
                                         float* hreg, int aoff, int wbase,
                                         int c, int g, int lane)
{
    short8v a0 = *(const short8v*)(hb + aoff);
    short8v a1 = *(const short8v*)(hb + aoff + 32);
#pragma unroll
    for (int nt = 0; nt < 4; ++nt) {
        f32x4 acc = {};
        short8v b0 = *(const short8v*)(wb + ((nt)     * 64 + lane) * 8);
        short8v b1 = *(const short8v*)(wb + ((4 + nt) * 64 + lane) * 8);
        acc = __builtin_amdgcn_mfma_f32_16x16x32_bf16(a0, b0, acc, 0, 0, 0);
        acc = __builtin_amdgcn_mfma_f32_16x16x32_bf16(a1, b1, acc, 0, 0, 0);
        const float bv = bias[nt * 16 + c];
#pragma unroll
        for (int r = 0; r < 4; ++r) {
            float v = acc[r] + bv;
            if (MODE == 1) v = fmaxf(v, 0.f);
            if (MODE == 2) { v += hreg[nt * 4 + r]; hreg[nt * 4 + r] = v; }
            if (MODE == 0) hreg[nt * 4 + r] = v;
            hb[(wbase + g * 4 + r) * STR + nt * 16 + c] = f2bf(v);
        }
    }
}

__launch_bounds__(256, 3)
__global__ void trunk_kernel(const float* __restrict__ z,
                             const float* __restrict__ x,
                             const float* __restrict__ b_in,
                             const float* __restrict__ rb1,
                             const float* __restrict__ rb2,
                             const u16* __restrict__ wsu,
                             const float* __restrict__ bout,
                             float* __restrict__ out,
                             float* __restrict__ kout)
{
    __shared__ __align__(16) u16 hbuf[64 * STR];    // 9216 B (in-place acts)
    __shared__ u16 xs[KS * 3 * XW];                 // 34776 B (bf16 x window)
    __shared__ float sbuf[4][32];                   // softmax cross-wave
    __shared__ float obuf[4][3][32];                // out cross-wave

    const int tid = threadIdx.x, lane = tid & 63, wave = tid >> 6;  // 0..3
    const int pix0 = blockIdx.x * 64;
    const int b = pix0 >> 12, rem0 = pix0 & 4095;
    const int hl = rem0 >> 6;

    // ---- stage z -> hbuf (bf16) ----
    {
        const int p = tid & 63, i0 = (tid >> 6) * 16;
        const float* zp = z + ((size_t)b * 64 + i0) * PPI + rem0 + p;
        u32* dst = (u32*)hbuf + p * (STR / 2) + i0 / 2;
#pragma unroll
        for (int i = 0; i < 16; i += 2) {
            float v0 = zp[(size_t)i * PPI];
            float v1 = zp[(size_t)(i + 1) * PPI];
            dst[i / 2] = (u32)f2bf(v0) | ((u32)f2bf(v1) << 16);
        }
    }
    // ---- stage reflected x window: rows hl*4-10..+10, cols -10..265 ----
    for (int u = tid; u < KS * 3 * XW; u += 256) {
        int t = u / XW;
        int j = u - t * XW;
        int ky = t / 3, cch = t - ky * 3;
        int row = reflect256(hl * 4 + ky - 10);
        int xcol = reflect256(j - 10);
        xs[u] = f2bf(x[(((size_t)b * 3 + cch) * 256 + row) * 256 + xcol]);
    }
    __syncthreads();

    // ---- 17-layer trunk, wave-private rows [wave*16, wave*16+16) ----
    const int c16 = lane & 15, g4 = lane >> 4;
    const int wbase = wave * 16;
    const int aoff = (wbase + c16) * STR + g4 * 8;
    float hreg[16];

    do_layer<0>(hbuf, wsu, b_in, hreg, aoff, wbase, c16, g4, lane);
#pragma unroll 1
    for (int l = 0; l < NB; ++l) {
        do_layer<1>(hbuf, wsu + (size_t)(1 + 2 * l) * 4096, rb1 + l * 64,
                    hreg, aoff, wbase, c16, g4, lane);
        do_layer<2>(hbuf, wsu + (size_t)(2 + 2 * l) * 4096, rb2 + l * 64,
                    hreg, aoff, wbase, c16, g4, lane);
    }
    __syncthreads();   // pass 1 reads other waves' h rows

    // ---- pass 1 (swapped operands, 32x32x16): D[tap][px], px on lane&31 ----
    const int c32 = lane & 31, hi2 = lane >> 5;
    const int wavepx = (wave >> 1) * 32;       // 0 or 32
    const int tbase = (wave & 1) * 7;          // 7 of 14 tap-tiles

    short8v bh[4];
#pragma unroll
    for (int kk = 0; kk < 4; ++kk)
        bh[kk] = *(const short8v*)(hbuf + (wavepx + c32) * STR + kk * 16 + hi2 * 8);

    float ssum = 0.f;
    u32 epack[56];
    const u16* wob = wsu + WOUT_OFF;
#pragma unroll
    for (int ti = 0; ti < 7; ++ti) {
        const int t = tbase + ti;
        f32x16 acc = {};
#pragma unroll
        for (int kk = 0; kk < 4; ++kk) {
            short8v aw = *(const short8v*)(wob + ((kk * 14 + t) * 64 + lane) * 8);
            acc = __builtin_amdgcn_mfma_f32_32x32x16_bf16(aw, bh[kk], acc, 0, 0, 0);
        }
#pragma unroll
        for (int rr = 0; rr < 8; ++rr) {
            const int r0 = 2 * rr;
            const int tap0 = t * 32 + (r0 & 3) + 8 * (r0 >> 2) + 4 * hi2;
            float e0 = __expf(acc[r0] + bout[tap0]);
            float e1 = __expf(acc[r0 + 1] + bout[tap0 + 1]);
            ssum += e0 + e1;
            epack[ti * 8 + rr] = (u32)f2bf(e0) | ((u32)f2bf(e1) << 16);
        }
    }
    ssum += __shfl_xor(ssum, 32);              // combine hi2 tap-halves
    if (lane < 32) sbuf[wave][lane] = ssum;
    __syncthreads();
    const float inv_s = 1.f / (ssum + sbuf[wave ^ 1][c32]);

    // ---- pass 2 + fused apply: p stores (128B segs, NT) + window FMAs ----
    const int pxl = wavepx + c32;              // == wl (block is one hl row)
    const int xcb = pxl * 4;                   // xs col base
    float* kbase = kout + (size_t)b * K2 * PPI + rem0 + pxl;
    float oacc0 = 0.f, oacc1 = 0.f, oacc2 = 0.f;

#pragma unroll
    for (int ti = 0; ti < 7; ++ti) {
        const int t = tbase + ti;
        int tap = t * 32 + 4 * hi2;
        int ky = tap / KS;
        int kx = tap - ky * KS;
#pragma unroll
        for (int rr = 0; rr < 8; ++rr) {
            const u32 ep = epack[ti * 8 + rr];
            float p0 = bflo(ep) * inv_s;
            float p1 = bfhi(ep) * inv_s;
            if (tap < K2) {
                __builtin_nontemporal_store(p0, kbase + (size_t)tap * PPI);
                const u16* xp = xs + ky * (3 * XW) + xcb + kx;
                oacc0 = fmaf(p0, u16f(xp[0]), oacc0);
                oacc1 = fmaf(p0, u16f(xp[XW]), oacc1);
                oacc2 = fmaf(p0, u16f(xp[2 * XW]), oacc2);
            }
            tap += 1; kx += 1; if (kx >= KS) { kx -= KS; ky += 1; }
            if (tap < K2) {
                __builtin_nontemporal_store(p1, kbase + (size_t)tap * PPI);
                const u16* xp = xs + ky * (3 * XW) + xcb + kx;
                oacc0 = fmaf(p1, u16f(xp[0]), oacc0);
                oacc1 = fmaf(p1, u16f(xp[XW]), oacc1);
                oacc2 = fmaf(p1, u16f(xp[2 * XW]), oacc2);
            }
            const int d = (rr & 1) ? 5 : 1;    // ..3 -> 8, ..11 -> 16, ...
            tap += d; kx += d; if (kx >= KS) { kx -= KS; ky += 1; }
        }
    }

    // ---- out reduction: tap-halves (xor32), then wave-pair via LDS ----
    oacc0 += __shfl_xor(oacc0, 32);
    oacc1 += __shfl_xor(oacc1, 32);
    oacc2 += __shfl_xor(oacc2, 32);
    if (lane < 32) {
        obuf[wave][0][lane] = oacc0;
        obuf[wave][1][lane] = oacc1;
        obuf[wave][2][lane] = oacc2;
    }
    __syncthreads();
    if ((wave & 1) == 0 && lane < 32) {
        float v0 = obuf[wave][0][lane] + obuf[wave + 1][0][lane];
        float v1 = obuf[wave][1][lane] + obuf[wave + 1][1][lane];
        float v2 = obuf[wave][2][lane] + obuf[wave + 1][2][lane];
        const int o = rem0 + wavepx + lane;
        out[((size_t)b * 3 + 0) * PPI + o] = v0;
        out[((size_t)b * 3 + 1) * PPI + o] = v1;
        out[((size_t)b * 3 + 2) * PPI + o] = v2;
    }
}

// ------------------------------------------------------------ launch -----
extern "C" void kernel_launch(void* const* d_in, const int* in_sizes, int n_in,
                              void* d_out, int out_size, void* d_ws, size_t ws_size,
                              hipStream_t stream)
{
    const float* x     = (const float*)d_in[0];
    const float* z     = (const float*)d_in[1];
    const float* w_in  = (const float*)d_in[2];
    const float* b_in  = (const float*)d_in[3];
    const float* rw1   = (const float*)d_in[4];
    const float* rb1   = (const float*)d_in[5];
    const float* rw2   = (const float*)d_in[6];
    const float* rb2   = (const float*)d_in[7];
    const float* w_out = (const float*)d_in[8];
    const float* b_out = (const float*)d_in[9];

    float* out  = (float*)d_out;
    float* kout = out + (size_t)16 * 3 * PPI;          // kernel output region
    u16*   wsu  = (u16*)d_ws;
    float* bout = (float*)((char*)d_ws + BOUT_BYTE);

    prep_kernel<<<(69632 + 28672 + 448 + 255) / 256, 256, 0, stream>>>(
        w_in, rw1, rw2, w_out, b_out, wsu, bout);

    trunk_kernel<<<NPIX / 64, 256, 0, stream>>>(
        z, x, b_in, rb1, rb2, wsu, bout, out, kout);
}

// Round 7
// 102.329 us; speedup vs baseline: 1.0059x; 1.0059x over previous
//
#include <hip/hip_runtime.h>
#include <math.h>

#define KS 21
#define K2 441
#define NB 8
#define PPI 4096
#define NPIX 65536
#define STR 72                     // LDS activation row stride (u16), 16B-aligned rows
#define XW 276

typedef unsigned short u16;
typedef unsigned int u32;
typedef short short8v __attribute__((ext_vector_type(8)));
typedef float f32x4 __attribute__((ext_vector_type(4)));
typedef float f32x16 __attribute__((ext_vector_type(16)));

// ws layout (u16 units): layer frags 17*4096 | wout frags 28672 | bout 448 f32
#define WOUT_OFF 69632
#define BOUT_BYTE 196608

__device__ __forceinline__ u16 f2bf(float x)
{
    union { float f; u32 u; } c; c.f = x;
    u32 r = c.u + 0x7FFF + ((c.u >> 16) & 1);
    return (u16)(r >> 16);
}
__device__ __forceinline__ float bflo(u32 w)
{ union { u32 u; float f; } c; c.u = w << 16; return c.f; }
__device__ __forceinline__ float bfhi(u32 w)
{ union { u32 u; float f; } c; c.u = w & 0xffff0000u; return c.f; }

// ---------------------------------------------------------------- prep ----
// Layer weights: 16x16x32 B-frag layout (n=lane&15, k=(lane>>4)*8+j, kk*32).
// w_out: 32x32x16 A-frag layout (m=tap=lane&31, k=kk*16+(lane>>5)*8+j),
//   14 tap-tiles x 4 kk. Padded taps (>=441) -> weight 0, bias -100.
__global__ void prep_kernel(const float* __restrict__ w_in,
                            const float* __restrict__ rw1,
                            const float* __restrict__ rw2,
                            const float* __restrict__ w_out,
                            const float* __restrict__ b_out,
                            u16* __restrict__ wsu, float* __restrict__ bout)
{
    int idx = blockIdx.x * 256 + threadIdx.x;
    if (idx < 69632) {
        int u = idx & 4095;
        int j = u & 7, lane = (u >> 3) & 63, frag = (u >> 9) & 7;
        int kk = frag >> 2, nt = frag & 3, layer = idx >> 12;
        int i = kk * 32 + (lane >> 4) * 8 + j;      // K (input ch)
        int o = nt * 16 + (lane & 15);              // N (output ch)
        const float* src;
        if (layer == 0) src = w_in;
        else if (layer & 1) src = rw1 + ((layer - 1) >> 1) * 4096;
        else src = rw2 + ((layer - 2) >> 1) * 4096;
        wsu[idx] = f2bf(src[o * 64 + i]);
    } else if (idx < 69632 + 28672) {
        int u = idx - 69632;
        int j = u & 7, lane = (u >> 3) & 63, t6 = u >> 9;   // 0..55
        int t = t6 % 14, kk = t6 / 14;
        int tap = t * 32 + (lane & 31);
        int i = kk * 16 + (lane >> 5) * 8 + j;
        wsu[idx] = f2bf((tap < K2) ? w_out[tap * 64 + i] : 0.f);
    } else if (idx < 69632 + 28672 + 448) {
        int tap = idx - (69632 + 28672);
        bout[tap] = (tap < K2) ? b_out[tap] : -100.f;
    }
}

// ------------------------------------------------------------- trunk -----
// Layer step, single in-place buffer (wave-private rows; reads complete
// before writes issue due to in-wave data dependence through the MFMA).
template <int MODE>
__device__ __forceinline__ void do_layer(u16* hb, const u16* __restrict__ wb,
                                         const float* __restrict__ bias,
                                         float* hreg, int aoff, int wbase,
                                         int c, int g, int lane)
{
    short8v a0 = *(const short8v*)(hb + aoff);
    short8v a1 = *(const short8v*)(hb + aoff + 32);
#pragma unroll
    for (int nt = 0; nt < 4; ++nt) {
        f32x4 acc = {};
        short8v b0 = *(const short8v*)(wb + ((nt)     * 64 + lane) * 8);
        short8v b1 = *(const short8v*)(wb + ((4 + nt) * 64 + lane) * 8);
        acc = __builtin_amdgcn_mfma_f32_16x16x32_bf16(a0, b0, acc, 0, 0, 0);
        acc = __builtin_amdgcn_mfma_f32_16x16x32_bf16(a1, b1, acc, 0, 0, 0);
        const float bv = bias[nt * 16 + c];
#pragma unroll
        for (int r = 0; r < 4; ++r) {
            float v = acc[r] + bv;
            if (MODE == 1) v = fmaxf(v, 0.f);
            if (MODE == 2) { v += hreg[nt * 4 + r]; hreg[nt * 4 + r] = v; }
            if (MODE == 0) hreg[nt * 4 + r] = v;
            hb[(wbase + g * 4 + r) * STR + nt * 16 + c] = f2bf(v);
        }
    }
}

__launch_bounds__(256, 4)
__global__ void trunk_kernel(const float* __restrict__ z,
                             const float* __restrict__ b_in,
                             const float* __restrict__ rb1,
                             const float* __restrict__ rb2,
                             const u16* __restrict__ wsu,
                             const float* __restrict__ bout,
                             float* __restrict__ kout)
{
    __shared__ __align__(16) u16 hbuf[64 * STR];    // 9216 B (in-place acts)
    __shared__ float bsh[448];                      // bout staged
    __shared__ float sbuf[4][32];                   // softmax cross-wave

    const int tid = threadIdx.x, lane = tid & 63, wave = tid >> 6;  // 0..3
    const int pix0 = blockIdx.x * 64;
    const int b = pix0 >> 12, rem0 = pix0 & 4095;

    // ---- stage z -> hbuf (bf16) ----
    {
        const int p = tid & 63, i0 = (tid >> 6) * 16;
        const float* zp = z + ((size_t)b * 64 + i0) * PPI + rem0 + p;
        u32* dst = (u32*)hbuf + p * (STR / 2) + i0 / 2;
#pragma unroll
        for (int i = 0; i < 16; i += 2) {
            float v0 = zp[(size_t)i * PPI];
            float v1 = zp[(size_t)(i + 1) * PPI];
            dst[i / 2] = (u32)f2bf(v0) | ((u32)f2bf(v1) << 16);
        }
    }
    // stage all 448 bias entries (256-thread block -> strided loop!)
    for (int u = tid; u < 448; u += 256) bsh[u] = bout[u];
    __syncthreads();

    // ---- 17-layer trunk, wave-private rows [wave*16, wave*16+16) ----
    const int c16 = lane & 15, g4 = lane >> 4;
    const int wbase = wave * 16;
    const int aoff = (wbase + c16) * STR + g4 * 8;
    float hreg[16];

    do_layer<0>(hbuf, wsu, b_in, hreg, aoff, wbase, c16, g4, lane);
#pragma unroll 1
    for (int l = 0; l < NB; ++l) {
        do_layer<1>(hbuf, wsu + (size_t)(1 + 2 * l) * 4096, rb1 + l * 64,
                    hreg, aoff, wbase, c16, g4, lane);
        do_layer<2>(hbuf, wsu + (size_t)(2 + 2 * l) * 4096, rb2 + l * 64,
                    hreg, aoff, wbase, c16, g4, lane);
    }
    __syncthreads();   // pass 1 reads other waves' h rows

    // ---- pass 1 (swapped operands, 32x32x16): D[tap][px], px on lane&31 ----
    const int c32 = lane & 31, hi2 = lane >> 5;
    const int wavepx = (wave >> 1) * 32;       // 0 or 32
    const int tbase = (wave & 1) * 7;          // 7 of 14 tap-tiles

    short8v bh[4];
#pragma unroll
    for (int kk = 0; kk < 4; ++kk)
        bh[kk] = *(const short8v*)(hbuf + (wavepx + c32) * STR + kk * 16 + hi2 * 8);

    float ssum = 0.f;
    u32 epack[56];
    const u16* wob = wsu + WOUT_OFF;
#pragma unroll
    for (int ti = 0; ti < 7; ++ti) {
        const int t = tbase + ti;
        f32x16 acc = {};
#pragma unroll
        for (int kk = 0; kk < 4; ++kk) {
            short8v aw = *(const short8v*)(wob + ((kk * 14 + t) * 64 + lane) * 8);
            acc = __builtin_amdgcn_mfma_f32_32x32x16_bf16(aw, bh[kk], acc, 0, 0, 0);
        }
#pragma unroll
        for (int rr = 0; rr < 8; ++rr) {
            const int r0 = 2 * rr;
            const int tap0 = t * 32 + (r0 & 3) + 8 * (r0 >> 2) + 4 * hi2;
            float e0 = __expf(acc[r0] + bsh[tap0]);
            float e1 = __expf(acc[r0 + 1] + bsh[tap0 + 1]);
            ssum += e0 + e1;
            epack[ti * 8 + rr] = (u32)f2bf(e0) | ((u32)f2bf(e1) << 16);
        }
    }
    ssum += __shfl_xor(ssum, 32);              // combine hi2 tap-halves
    if (lane < 32) sbuf[wave][lane] = ssum;
    __syncthreads();
    const float inv_s = 1.f / (ssum + sbuf[wave ^ 1][c32]);

    // ---- pass 2: normalized p straight from registers, full 128B lines ----
    const int pxl = wavepx + c32;
    float* kbase = kout + (size_t)b * K2 * PPI + rem0 + pxl;
#pragma unroll
    for (int ti = 0; ti < 7; ++ti) {
        int tap = (tbase + ti) * 32 + 4 * hi2;
#pragma unroll
        for (int rr = 0; rr < 8; ++rr) {
            const u32 ep = epack[ti * 8 + rr];
            float p0 = bflo(ep) * inv_s;
            float p1 = bfhi(ep) * inv_s;
            if (tap < K2)     kbase[(size_t)tap * PPI] = p0;
            if (tap + 1 < K2) kbase[(size_t)(tap + 1) * PPI] = p1;
            tap += (rr & 1) ? 6 : 2;
        }
    }
}

// ------------------------------------------------------------- apply -----
__device__ __forceinline__ int reflect256(int v)
{
    v = (v < 0) ? -v : v;
    return (v > 255) ? (510 - v) : v;
}

// 64 px (one low-res row) per block; x footprint staged in LDS as bf16;
// 4-way ky split (6+5+5+5) + LDS combine.
__launch_bounds__(256)
__global__ void apply_kernel(const float* __restrict__ x,
                             const float* __restrict__ kbuf,
                             float* __restrict__ out)
{
    __shared__ u16 xs[KS * 3 * XW];          // 34.8 KB
    __shared__ float sm[4][3][64];

    const int tid = threadIdx.x;
    const int pix0 = blockIdx.x * 64;
    const int b = pix0 >> 12, rem0 = pix0 & 4095;
    const int hl = rem0 >> 6;

    // ---- stage reflected x window: rows hl*4-10..+10, cols -10..265 ----
    const int total = KS * 3 * XW;           // 17388
    for (int u = tid; u < total; u += 256) {
        int t = u / XW;
        int j = u - t * XW;
        int ky = t / 3, cch = t - ky * 3;
        int row = reflect256(hl * 4 + ky - 10);
        int xcol = reflect256(j - 10);
        xs[u] = f2bf(x[(((size_t)b * 3 + cch) * 256 + row) * 256 + xcol]);
    }
    __syncthreads();

    const int pxl = tid & 63, part = tid >> 6;
    const int ky0 = (part == 0) ? 0 : 1 + part * 5;    // 0,6,11,16
    const int ky1 = (part == 0) ? 6 : ky0 + 5;

    const float* kpix = kbuf + (size_t)b * K2 * PPI + rem0 + pxl;

    float acc0 = 0.f, acc1 = 0.f, acc2 = 0.f;

#pragma unroll 1
    for (int ky = ky0; ky < ky1; ++ky) {
        float pv[KS];
#pragma unroll
        for (int kx = 0; kx < KS; ++kx)
            pv[kx] = kpix[(size_t)(ky * KS + kx) * PPI];
#pragma unroll
        for (int cch = 0; cch < 3; ++cch) {
            const u32* xr = (const u32*)(xs + (ky * 3 + cch) * XW + pxl * 4);
            float xv[22];
#pragma unroll
            for (int q = 0; q < 11; ++q) {
                u32 w = xr[q];
                xv[2 * q] = bflo(w);
                xv[2 * q + 1] = bfhi(w);
            }
            float a = 0.f;
#pragma unroll
            for (int kx = 0; kx < KS; ++kx) a = fmaf(pv[kx], xv[kx], a);
            if (cch == 0) acc0 += a;
            else if (cch == 1) acc1 += a;
            else acc2 += a;
        }
    }
    sm[part][0][pxl] = acc0;
    sm[part][1][pxl] = acc1;
    sm[part][2][pxl] = acc2;
    __syncthreads();
    if (part == 0) {
#pragma unroll
        for (int cch = 0; cch < 3; ++cch) {
            float v = sm[0][cch][pxl] + sm[1][cch][pxl] +
                      sm[2][cch][pxl] + sm[3][cch][pxl];
            out[((size_t)b * 3 + cch) * PPI + rem0 + pxl] = v;
        }
    }
}

// ------------------------------------------------------------ launch -----
extern "C" void kernel_launch(void* const* d_in, const int* in_sizes, int n_in,
                              void* d_out, int out_size, void* d_ws, size_t ws_size,
                              hipStream_t stream)
{
    const float* x     = (const float*)d_in[0];
    const float* z     = (const float*)d_in[1];
    const float* w_in  = (const float*)d_in[2];
    const float* b_in  = (const float*)d_in[3];
    const float* rw1   = (const float*)d_in[4];
    const float* rb1   = (const float*)d_in[5];
    const float* rw2   = (const float*)d_in[6];
    const float* rb2   = (const float*)d_in[7];
    const float* w_out = (const float*)d_in[8];
    const float* b_out = (const float*)d_in[9];

    float* out  = (float*)d_out;
    float* kout = out + (size_t)16 * 3 * PPI;          // kernel output region
    u16*   wsu  = (u16*)d_ws;
    float* bout = (float*)((char*)d_ws + BOUT_BYTE);

    prep_kernel<<<(69632 + 28672 + 448 + 255) / 256, 256, 0, stream>>>(
        w_in, rw1, rw2, w_out, b_out, wsu, bout);

    trunk_kernel<<<NPIX / 64, 256, 0, stream>>>(
        z, b_in, rb1, rb2, wsu, bout, kout);

    apply_kernel<<<NPIX / 64, 256, 0, stream>>>(x, kout, out);
}

// Round 8
// 99.589 us; speedup vs baseline: 1.0335x; 1.0275x over previous
//
#include <hip/hip_runtime.h>
#include <math.h>

#define KS 21
#define K2 441
#define NB 8
#define PPI 4096
#define NPIX 65536
#define STR 72                     // LDS activation row stride (u16), 16B-aligned rows
#define XW 276

typedef unsigned short u16;
typedef unsigned int u32;
typedef short short8v __attribute__((ext_vector_type(8)));
typedef float f32x4 __attribute__((ext_vector_type(4)));
typedef float f32x16 __attribute__((ext_vector_type(16)));

// ws layout (u16 units): layer frags 17*4096 | wout frags 28672 | bout 448 f32
#define WOUT_OFF 69632
#define BOUT_BYTE 196608

__device__ __forceinline__ u16 f2bf(float x)
{
    union { float f; u32 u; } c; c.f = x;
    u32 r = c.u + 0x7FFF + ((c.u >> 16) & 1);
    return (u16)(r >> 16);
}
__device__ __forceinline__ float bflo(u32 w)
{ union { u32 u; float f; } c; c.u = w << 16; return c.f; }
__device__ __forceinline__ float bfhi(u32 w)
{ union { u32 u; float f; } c; c.u = w & 0xffff0000u; return c.f; }

// XCD-aware bijective swizzle for 1024-block grids (1024 % 8 == 0):
// hardware round-robins blockIdx%8 across XCDs; remap so XCD x gets 128
// CONSECUTIVE logical blocks = 8192 consecutive pixels = 2 whole images.
// => every kout tap-plane is written by exactly one XCD's L2 (linear
// writeback streams instead of 8-way interleaved 256B slices).
__device__ __forceinline__ int xcd_swz(int i)
{
    return ((i & 7) << 7) | (i >> 3);
}

// ---------------------------------------------------------------- prep ----
// Layer weights: 16x16x32 B-frag layout (n=lane&15, k=(lane>>4)*8+j, kk*32).
// w_out: 32x32x16 A-frag layout (m=tap=lane&31, k=kk*16+(lane>>5)*8+j),
//   14 tap-tiles x 4 kk. Padded taps (>=441) -> weight 0, bias -100.
__global__ void prep_kernel(const float* __restrict__ w_in,
                            const float* __restrict__ rw1,
                            const float* __restrict__ rw2,
                            const float* __restrict__ w_out,
                            const float* __restrict__ b_out,
                            u16* __restrict__ wsu, float* __restrict__ bout)
{
    int idx = blockIdx.x * 256 + threadIdx.x;
    if (idx < 69632) {
        int u = idx & 4095;
        int j = u & 7, lane = (u >> 3) & 63, frag = (u >> 9) & 7;
        int kk = frag >> 2, nt = frag & 3, layer = idx >> 12;
        int i = kk * 32 + (lane >> 4) * 8 + j;      // K (input ch)
        int o = nt * 16 + (lane & 15);              // N (output ch)
        const float* src;
        if (layer == 0) src = w_in;
        else if (layer & 1) src = rw1 + ((layer - 1) >> 1) * 4096;
        else src = rw2 + ((layer - 2) >> 1) * 4096;
        wsu[idx] = f2bf(src[o * 64 + i]);
    } else if (idx < 69632 + 28672) {
        int u = idx - 69632;
        int j = u & 7, lane = (u >> 3) & 63, t6 = u >> 9;   // 0..55
        int t = t6 % 14, kk = t6 / 14;
        int tap = t * 32 + (lane & 31);
        int i = kk * 16 + (lane >> 5) * 8 + j;
        wsu[idx] = f2bf((tap < K2) ? w_out[tap * 64 + i] : 0.f);
    } else if (idx < 69632 + 28672 + 448) {
        int tap = idx - (69632 + 28672);
        bout[tap] = (tap < K2) ? b_out[tap] : -100.f;
    }
}

// ------------------------------------------------------------- trunk -----
// Layer step, single in-place buffer (wave-private rows; reads complete
// before writes issue due to in-wave data dependence through the MFMA).
template <int MODE>
__device__ __forceinline__ void do_layer(u16* hb, const u16* __restrict__ wb,
                                         const float* __restrict__ bias,
                                         float* hreg, int aoff, int wbase,
                                         int c, int g, int lane)
{
    short8v a0 = *(const short8v*)(hb + aoff);
    short8v a1 = *(const short8v*)(hb + aoff + 32);
#pragma unroll
    for (int nt = 0; nt < 4; ++nt) {
        f32x4 acc = {};
        short8v b0 = *(const short8v*)(wb + ((nt)     * 64 + lane) * 8);
        short8v b1 = *(const short8v*)(wb + ((4 + nt) * 64 + lane) * 8);
        acc = __builtin_amdgcn_mfma_f32_16x16x32_bf16(a0, b0, acc, 0, 0, 0);
        acc = __builtin_amdgcn_mfma_f32_16x16x32_bf16(a1, b1, acc, 0, 0, 0);
        const float bv = bias[nt * 16 + c];
#pragma unroll
        for (int r = 0; r < 4; ++r) {
            float v = acc[r] + bv;
            if (MODE == 1) v = fmaxf(v, 0.f);
            if (MODE == 2) { v += hreg[nt * 4 + r]; hreg[nt * 4 + r] = v; }
            if (MODE == 0) hreg[nt * 4 + r] = v;
            hb[(wbase + g * 4 + r) * STR + nt * 16 + c] = f2bf(v);
        }
    }
}

__launch_bounds__(256, 4)
__global__ void trunk_kernel(const float* __restrict__ z,
                             const float* __restrict__ b_in,
                             const float* __restrict__ rb1,
                             const float* __restrict__ rb2,
                             const u16* __restrict__ wsu,
                             const float* __restrict__ bout,
                             float* __restrict__ kout)
{
    __shared__ __align__(16) u16 hbuf[64 * STR];    // 9216 B (in-place acts)
    __shared__ float bsh[448];                      // bout staged
    __shared__ float sbuf[4][32];                   // softmax cross-wave

    const int tid = threadIdx.x, lane = tid & 63, wave = tid >> 6;  // 0..3
    const int pix0 = xcd_swz(blockIdx.x) * 64;
    const int b = pix0 >> 12, rem0 = pix0 & 4095;

    // ---- stage z -> hbuf (bf16) ----
    {
        const int p = tid & 63, i0 = (tid >> 6) * 16;
        const float* zp = z + ((size_t)b * 64 + i0) * PPI + rem0 + p;
        u32* dst = (u32*)hbuf + p * (STR / 2) + i0 / 2;
#pragma unroll
        for (int i = 0; i < 16; i += 2) {
            float v0 = zp[(size_t)i * PPI];
            float v1 = zp[(size_t)(i + 1) * PPI];
            dst[i / 2] = (u32)f2bf(v0) | ((u32)f2bf(v1) << 16);
        }
    }
    // stage all 448 bias entries (256-thread block -> strided loop)
    for (int u = tid; u < 448; u += 256) bsh[u] = bout[u];
    __syncthreads();

    // ---- 17-layer trunk, wave-private rows [wave*16, wave*16+16) ----
    const int c16 = lane & 15, g4 = lane >> 4;
    const int wbase = wave * 16;
    const int aoff = (wbase + c16) * STR + g4 * 8;
    float hreg[16];

    do_layer<0>(hbuf, wsu, b_in, hreg, aoff, wbase, c16, g4, lane);
#pragma unroll 1
    for (int l = 0; l < NB; ++l) {
        do_layer<1>(hbuf, wsu + (size_t)(1 + 2 * l) * 4096, rb1 + l * 64,
                    hreg, aoff, wbase, c16, g4, lane);
        do_layer<2>(hbuf, wsu + (size_t)(2 + 2 * l) * 4096, rb2 + l * 64,
                    hreg, aoff, wbase, c16, g4, lane);
    }
    __syncthreads();   // pass 1 reads other waves' h rows

    // ---- pass 1 (swapped operands, 32x32x16): D[tap][px], px on lane&31 ----
    const int c32 = lane & 31, hi2 = lane >> 5;
    const int wavepx = (wave >> 1) * 32;       // 0 or 32
    const int tbase = (wave & 1) * 7;          // 7 of 14 tap-tiles

    short8v bh[4];
#pragma unroll
    for (int kk = 0; kk < 4; ++kk)
        bh[kk] = *(const short8v*)(hbuf + (wavepx + c32) * STR + kk * 16 + hi2 * 8);

    float ssum = 0.f;
    u32 epack[56];
    const u16* wob = wsu + WOUT_OFF;
#pragma unroll
    for (int ti = 0; ti < 7; ++ti) {
        const int t = tbase + ti;
        f32x16 acc = {};
#pragma unroll
        for (int kk = 0; kk < 4; ++kk) {
            short8v aw = *(const short8v*)(wob + ((kk * 14 + t) * 64 + lane) * 8);
            acc = __builtin_amdgcn_mfma_f32_32x32x16_bf16(aw, bh[kk], acc, 0, 0, 0);
        }
#pragma unroll
        for (int rr = 0; rr < 8; ++rr) {
            const int r0 = 2 * rr;
            const int tap0 = t * 32 + (r0 & 3) + 8 * (r0 >> 2) + 4 * hi2;
            float e0 = __expf(acc[r0] + bsh[tap0]);
            float e1 = __expf(acc[r0 + 1] + bsh[tap0 + 1]);
            ssum += e0 + e1;
            epack[ti * 8 + rr] = (u32)f2bf(e0) | ((u32)f2bf(e1) << 16);
        }
    }
    ssum += __shfl_xor(ssum, 32);              // combine hi2 tap-halves
    if (lane < 32) sbuf[wave][lane] = ssum;
    __syncthreads();
    const float inv_s = 1.f / (ssum + sbuf[wave ^ 1][c32]);

    // ---- pass 2: normalized p straight from registers, full 128B lines ----
    const int pxl = wavepx + c32;
    float* kbase = kout + (size_t)b * K2 * PPI + rem0 + pxl;
#pragma unroll
    for (int ti = 0; ti < 7; ++ti) {
        int tap = (tbase + ti) * 32 + 4 * hi2;
#pragma unroll
        for (int rr = 0; rr < 8; ++rr) {
            const u32 ep = epack[ti * 8 + rr];
            float p0 = bflo(ep) * inv_s;
            float p1 = bfhi(ep) * inv_s;
            if (tap < K2)     kbase[(size_t)tap * PPI] = p0;
            if (tap + 1 < K2) kbase[(size_t)(tap + 1) * PPI] = p1;
            tap += (rr & 1) ? 6 : 2;
        }
    }
}

// ------------------------------------------------------------- apply -----
__device__ __forceinline__ int reflect256(int v)
{
    v = (v < 0) ? -v : v;
    return (v > 255) ? (510 - v) : v;
}

// 64 px (one low-res row) per block; x footprint staged in LDS as bf16;
// 4-way ky split (6+5+5+5) + LDS combine.
__launch_bounds__(256)
__global__ void apply_kernel(const float* __restrict__ x,
                             const float* __restrict__ kbuf,
                             float* __restrict__ out)
{
    __shared__ u16 xs[KS * 3 * XW];          // 34.8 KB
    __shared__ float sm[4][3][64];

    const int tid = threadIdx.x;
    const int pix0 = xcd_swz(blockIdx.x) * 64;   // same XCD locality as trunk
    const int b = pix0 >> 12, rem0 = pix0 & 4095;
    const int hl = rem0 >> 6;

    // ---- stage reflected x window: rows hl*4-10..+10, cols -10..265 ----
    const int total = KS * 3 * XW;           // 17388
    for (int u = tid; u < total; u += 256) {
        int t = u / XW;
        int j = u - t * XW;
        int ky = t / 3, cch = t - ky * 3;
        int row = reflect256(hl * 4 + ky - 10);
        int xcol = reflect256(j - 10);
        xs[u] = f2bf(x[(((size_t)b * 3 + cch) * 256 + row) * 256 + xcol]);
    }
    __syncthreads();

    const int pxl = tid & 63, part = tid >> 6;
    const int ky0 = (part == 0) ? 0 : 1 + part * 5;    // 0,6,11,16
    const int ky1 = (part == 0) ? 6 : ky0 + 5;

    const float* kpix = kbuf + (size_t)b * K2 * PPI + rem0 + pxl;

    float acc0 = 0.f, acc1 = 0.f, acc2 = 0.f;

#pragma unroll 1
    for (int ky = ky0; ky < ky1; ++ky) {
        float pv[KS];
#pragma unroll
        for (int kx = 0; kx < KS; ++kx)
            pv[kx] = kpix[(size_t)(ky * KS + kx) * PPI];
#pragma unroll
        for (int cch = 0; cch < 3; ++cch) {
            const u32* xr = (const u32*)(xs + (ky * 3 + cch) * XW + pxl * 4);
            float xv[22];
#pragma unroll
            for (int q = 0; q < 11; ++q) {
                u32 w = xr[q];
                xv[2 * q] = bflo(w);
                xv[2 * q + 1] = bfhi(w);
            }
            float a = 0.f;
#pragma unroll
            for (int kx = 0; kx < KS; ++kx) a = fmaf(pv[kx], xv[kx], a);
            if (cch == 0) acc0 += a;
            else if (cch == 1) acc1 += a;
            else acc2 += a;
        }
    }
    sm[part][0][pxl] = acc0;
    sm[part][1][pxl] = acc1;
    sm[part][2][pxl] = acc2;
    __syncthreads();
    if (part == 0) {
#pragma unroll
        for (int cch = 0; cch < 3; ++cch) {
            float v = sm[0][cch][pxl] + sm[1][cch][pxl] +
                      sm[2][cch][pxl] + sm[3][cch][pxl];
            out[((size_t)b * 3 + cch) * PPI + rem0 + pxl] = v;
        }
    }
}

// ------------------------------------------------------------ launch -----
extern "C" void kernel_launch(void* const* d_in, const int* in_sizes, int n_in,
                              void* d_out, int out_size, void* d_ws, size_t ws_size,
                              hipStream_t stream)
{
    const float* x     = (const float*)d_in[0];
    const float* z     = (const float*)d_in[1];
    const float* w_in  = (const float*)d_in[2];
    const float* b_in  = (const float*)d_in[3];
    const float* rw1   = (const float*)d_in[4];
    const float* rb1   = (const float*)d_in[5];
    const float* rw2   = (const float*)d_in[6];
    const float* rb2   = (const float*)d_in[7];
    const float* w_out = (const float*)d_in[8];
    const float* b_out = (const float*)d_in[9];

    float* out  = (float*)d_out;
    float* kout = out + (size_t)16 * 3 * PPI;          // kernel output region
    u16*   wsu  = (u16*)d_ws;
    float* bout = (float*)((char*)d_ws + BOUT_BYTE);

    prep_kernel<<<(69632 + 28672 + 448 + 255) / 256, 256, 0, stream>>>(
        w_in, rw1, rw2, w_out, b_out, wsu, bout);

    trunk_kernel<<<NPIX / 64, 256, 0, stream>>>(
        z, b_in, rb1, rb2, wsu, bout, kout);

    apply_kernel<<<NPIX / 64, 256, 0, stream>>>(x, kout, out);
}

// Round 9
// 97.205 us; speedup vs baseline: 1.0589x; 1.0245x over previous
//
#include <hip/hip_runtime.h>
#include <math.h>

#define KS 21
#define K2 441
#define NB 8
#define PPI 4096
#define NPIX 65536
#define STR 72                     // LDS activation row stride (u16), 16B-aligned rows
#define XW 276
#define BPX 256                    // pixels per block (trunk & apply)

typedef unsigned short u16;
typedef unsigned int u32;
typedef short short8v __attribute__((ext_vector_type(8)));
typedef float f32x4 __attribute__((ext_vector_type(4)));
typedef float f32x16 __attribute__((ext_vector_type(16)));

// ws layout (u16 units): layer frags 17*4096 | wout frags 28672 | bout 448 f32
#define WOUT_OFF 69632
#define BOUT_BYTE 196608

__device__ __forceinline__ u16 f2bf(float x)
{
    union { float f; u32 u; } c; c.f = x;
    u32 r = c.u + 0x7FFF + ((c.u >> 16) & 1);
    return (u16)(r >> 16);
}
__device__ __forceinline__ float bflo(u32 w)
{ union { u32 u; float f; } c; c.u = w << 16; return c.f; }
__device__ __forceinline__ float bfhi(u32 w)
{ union { u32 u; float f; } c; c.u = w & 0xffff0000u; return c.f; }

// XCD-aware bijective swizzle for 256-block grids: XCD x owns 32
// consecutive logical blocks = 8192 consecutive px = 2 whole images.
__device__ __forceinline__ int xcd_swz(int i)
{
    return ((i & 7) << 5) | (i >> 3);
}

// ---------------------------------------------------------------- prep ----
// Layer weights: 16x16x32 B-frag layout (n=lane&15, k=(lane>>4)*8+j, kk*32).
// w_out: 32x32x16 A-frag layout (m=tap=lane&31, k=kk*16+(lane>>5)*8+j),
//   14 tap-tiles x 4 kk. Padded taps (>=441) -> weight 0, bias -100.
__global__ void prep_kernel(const float* __restrict__ w_in,
                            const float* __restrict__ rw1,
                            const float* __restrict__ rw2,
                            const float* __restrict__ w_out,
                            const float* __restrict__ b_out,
                            u16* __restrict__ wsu, float* __restrict__ bout)
{
    int idx = blockIdx.x * 256 + threadIdx.x;
    if (idx < 69632) {
        int u = idx & 4095;
        int j = u & 7, lane = (u >> 3) & 63, frag = (u >> 9) & 7;
        int kk = frag >> 2, nt = frag & 3, layer = idx >> 12;
        int i = kk * 32 + (lane >> 4) * 8 + j;      // K (input ch)
        int o = nt * 16 + (lane & 15);              // N (output ch)
        const float* src;
        if (layer == 0) src = w_in;
        else if (layer & 1) src = rw1 + ((layer - 1) >> 1) * 4096;
        else src = rw2 + ((layer - 2) >> 1) * 4096;
        wsu[idx] = f2bf(src[o * 64 + i]);
    } else if (idx < 69632 + 28672) {
        int u = idx - 69632;
        int j = u & 7, lane = (u >> 3) & 63, t6 = u >> 9;   // 0..55
        int t = t6 % 14, kk = t6 / 14;
        int tap = t * 32 + (lane & 31);
        int i = kk * 16 + (lane >> 5) * 8 + j;
        wsu[idx] = f2bf((tap < K2) ? w_out[tap * 64 + i] : 0.f);
    } else if (idx < 69632 + 28672 + 448) {
        int tap = idx - (69632 + 28672);
        bout[tap] = (tap < K2) ? b_out[tap] : -100.f;
    }
}

// ------------------------------------------------------------- trunk -----
// Layer step, single in-place buffer (wave-private rows).
template <int MODE>
__device__ __forceinline__ void do_layer(u16* hb, const u16* __restrict__ wb,
                                         const float* __restrict__ bias,
                                         float* hreg, int aoff, int wbase,
                                         int c, int g, int lane)
{
    short8v a0 = *(const short8v*)(hb + aoff);
    short8v a1 = *(const short8v*)(hb + aoff + 32);
#pragma unroll
    for (int nt = 0; nt < 4; ++nt) {
        f32x4 acc = {};
        short8v b0 = *(const short8v*)(wb + ((nt)     * 64 + lane) * 8);
        short8v b1 = *(const short8v*)(wb + ((4 + nt) * 64 + lane) * 8);
        acc = __builtin_amdgcn_mfma_f32_16x16x32_bf16(a0, b0, acc, 0, 0, 0);
        acc = __builtin_amdgcn_mfma_f32_16x16x32_bf16(a1, b1, acc, 0, 0, 0);
        const float bv = bias[nt * 16 + c];
#pragma unroll
        for (int r = 0; r < 4; ++r) {
            float v = acc[r] + bv;
            if (MODE == 1) v = fmaxf(v, 0.f);
            if (MODE == 2) { v += hreg[nt * 4 + r]; hreg[nt * 4 + r] = v; }
            if (MODE == 0) hreg[nt * 4 + r] = v;
            hb[(wbase + g * 4 + r) * STR + nt * 16 + c] = f2bf(v);
        }
    }
}

__launch_bounds__(1024, 1)
__global__ void trunk_kernel(const float* __restrict__ z,
                             const float* __restrict__ b_in,
                             const float* __restrict__ rb1,
                             const float* __restrict__ rb2,
                             const u16* __restrict__ wsu,
                             const float* __restrict__ bout,
                             float* __restrict__ kout)
{
    __shared__ __align__(16) u16 hbuf[BPX * STR];   // 36864 B (in-place acts)
    __shared__ float bsh[448];                      // bout staged
    __shared__ float sbuf[16][32];                  // softmax cross-wave

    const int tid = threadIdx.x, lane = tid & 63, wave = tid >> 6;  // 0..15
    const int pix0 = xcd_swz(blockIdx.x) * BPX;
    const int b = pix0 >> 12, rem0 = pix0 & 4095;

    // ---- stage z -> hbuf (bf16); thread (p,g) stages px p, 16 channels ----
    {
        const int p = tid & 255, i0 = (tid >> 8) * 16;
        const float* zp = z + ((size_t)b * 64 + i0) * PPI + rem0 + p;
        u32* dst = (u32*)hbuf + p * (STR / 2) + i0 / 2;
#pragma unroll
        for (int i = 0; i < 16; i += 2) {
            float v0 = zp[(size_t)i * PPI];
            float v1 = zp[(size_t)(i + 1) * PPI];
            dst[i / 2] = (u32)f2bf(v0) | ((u32)f2bf(v1) << 16);
        }
    }
    if (tid < 448) bsh[tid] = bout[tid];
    __syncthreads();

    // ---- 17-layer trunk, wave-private rows [wave*16, wave*16+16) ----
    const int c16 = lane & 15, g4 = lane >> 4;
    const int wbase = wave * 16;
    const int aoff = (wbase + c16) * STR + g4 * 8;
    float hreg[16];

    do_layer<0>(hbuf, wsu, b_in, hreg, aoff, wbase, c16, g4, lane);
#pragma unroll 1
    for (int l = 0; l < NB; ++l) {
        do_layer<1>(hbuf, wsu + (size_t)(1 + 2 * l) * 4096, rb1 + l * 64,
                    hreg, aoff, wbase, c16, g4, lane);
        do_layer<2>(hbuf, wsu + (size_t)(2 + 2 * l) * 4096, rb2 + l * 64,
                    hreg, aoff, wbase, c16, g4, lane);
    }
    __syncthreads();   // pass 1 reads other waves' h rows

    // ---- pass 1 (swapped operands, 32x32x16): D[tap][px], px on lane&31 ----
    const int c32 = lane & 31, hi2 = lane >> 5;
    const int wavepx = (wave >> 1) * 32;       // 0..224
    const int tbase = (wave & 1) * 7;          // 7 of 14 tap-tiles

    short8v bh[4];
#pragma unroll
    for (int kk = 0; kk < 4; ++kk)
        bh[kk] = *(const short8v*)(hbuf + (wavepx + c32) * STR + kk * 16 + hi2 * 8);

    float ssum = 0.f;
    u32 epack[56];
    const u16* wob = wsu + WOUT_OFF;
#pragma unroll
    for (int ti = 0; ti < 7; ++ti) {
        const int t = tbase + ti;
        f32x16 acc = {};
#pragma unroll
        for (int kk = 0; kk < 4; ++kk) {
            short8v aw = *(const short8v*)(wob + ((kk * 14 + t) * 64 + lane) * 8);
            acc = __builtin_amdgcn_mfma_f32_32x32x16_bf16(aw, bh[kk], acc, 0, 0, 0);
        }
#pragma unroll
        for (int rr = 0; rr < 8; ++rr) {
            const int r0 = 2 * rr;
            const int tap0 = t * 32 + (r0 & 3) + 8 * (r0 >> 2) + 4 * hi2;
            float e0 = __expf(acc[r0] + bsh[tap0]);
            float e1 = __expf(acc[r0 + 1] + bsh[tap0 + 1]);
            ssum += e0 + e1;
            epack[ti * 8 + rr] = (u32)f2bf(e0) | ((u32)f2bf(e1) << 16);
        }
    }
    ssum += __shfl_xor(ssum, 32);              // combine hi2 tap-halves
    if (lane < 32) sbuf[wave][lane] = ssum;
    __syncthreads();
    const float inv_s = 1.f / (ssum + sbuf[wave ^ 1][c32]);

    // ---- pass 2: normalized p straight from registers; the 8 same-parity
    //      waves cover 256 contiguous px per tap -> 1KB HBM chunks ----
    const int pxl = wavepx + c32;
    float* kbase = kout + (size_t)b * K2 * PPI + rem0 + pxl;
#pragma unroll
    for (int ti = 0; ti < 7; ++ti) {
        int tap = (tbase + ti) * 32 + 4 * hi2;
#pragma unroll
        for (int rr = 0; rr < 8; ++rr) {
            const u32 ep = epack[ti * 8 + rr];
            float p0 = bflo(ep) * inv_s;
            float p1 = bfhi(ep) * inv_s;
            if (tap < K2)     kbase[(size_t)tap * PPI] = p0;
            if (tap + 1 < K2) kbase[(size_t)(tap + 1) * PPI] = p1;
            tap += (rr & 1) ? 6 : 2;
        }
    }
}

// ------------------------------------------------------------- apply -----
__device__ __forceinline__ int reflect256(int v)
{
    v = (v < 0) ? -v : v;
    return (v > 255) ? (510 - v) : v;
}

// 256 px (4 low-res rows) per block; x footprint (33 hi-res rows) in LDS;
// 4-way ky split (6+5+5+5) + LDS combine. Per tap the block reads 1KB
// contiguous from kout.
__launch_bounds__(1024, 1)
__global__ void apply_kernel(const float* __restrict__ x,
                             const float* __restrict__ kbuf,
                             float* __restrict__ out)
{
    __shared__ u16 xs[33 * 3 * XW];          // 54.6 KB
    __shared__ float sm[4][3][BPX];          // 12 KB

    const int tid = threadIdx.x;
    const int pix0 = xcd_swz(blockIdx.x) * BPX;
    const int b = pix0 >> 12, rem0 = pix0 & 4095;
    const int hl0 = rem0 >> 6;

    // ---- stage reflected x: rows hl0*4-10 .. hl0*4+22, cols -10..265 ----
    const int total = 33 * 3 * XW;           // 27324
    for (int u = tid; u < total; u += 1024) {
        int t = u / XW;                      // rr*3 + cch
        int j = u - t * XW;
        int rr = t / 3, cch = t - rr * 3;
        int row = reflect256(hl0 * 4 + rr - 10);
        int xcol = reflect256(j - 10);
        xs[u] = f2bf(x[(((size_t)b * 3 + cch) * 256 + row) * 256 + xcol]);
    }
    __syncthreads();

    const int pxl = tid & 255, part = tid >> 8;
    const int hlr = pxl >> 6, wl = pxl & 63;         // row-in-block, col
    const int ky0 = (part == 0) ? 0 : 1 + part * 5;  // 0,6,11,16
    const int ky1 = (part == 0) ? 6 : ky0 + 5;

    const float* kpix = kbuf + (size_t)b * K2 * PPI + rem0 + pxl;

    float acc0 = 0.f, acc1 = 0.f, acc2 = 0.f;

#pragma unroll 1
    for (int ky = ky0; ky < ky1; ++ky) {
        const int r = hlr * 4 + ky;                  // xs row index
        float pv[KS];
#pragma unroll
        for (int kx = 0; kx < KS; ++kx)
            pv[kx] = kpix[(size_t)(ky * KS + kx) * PPI];
#pragma unroll
        for (int cch = 0; cch < 3; ++cch) {
            const u32* xr = (const u32*)(xs + (r * 3 + cch) * XW + wl * 4);
            float xv[22];
#pragma unroll
            for (int q = 0; q < 11; ++q) {
                u32 w = xr[q];
                xv[2 * q] = bflo(w);
                xv[2 * q + 1] = bfhi(w);
            }
            float a = 0.f;
#pragma unroll
            for (int kx = 0; kx < KS; ++kx) a = fmaf(pv[kx], xv[kx], a);
            if (cch == 0) acc0 += a;
            else if (cch == 1) acc1 += a;
            else acc2 += a;
        }
    }
    sm[part][0][pxl] = acc0;
    sm[part][1][pxl] = acc1;
    sm[part][2][pxl] = acc2;
    __syncthreads();
    if (part == 0) {
#pragma unroll
        for (int cch = 0; cch < 3; ++cch) {
            float v = sm[0][cch][pxl] + sm[1][cch][pxl] +
                      sm[2][cch][pxl] + sm[3][cch][pxl];
            out[((size_t)b * 3 + cch) * PPI + rem0 + pxl] = v;
        }
    }
}

// ------------------------------------------------------------ launch -----
extern "C" void kernel_launch(void* const* d_in, const int* in_sizes, int n_in,
                              void* d_out, int out_size, void* d_ws, size_t ws_size,
                              hipStream_t stream)
{
    const float* x     = (const float*)d_in[0];
    const float* z     = (const float*)d_in[1];
    const float* w_in  = (const float*)d_in[2];
    const float* b_in  = (const float*)d_in[3];
    const float* rw1   = (const float*)d_in[4];
    const float* rb1   = (const float*)d_in[5];
    const float* rw2   = (const float*)d_in[6];
    const float* rb2   = (const float*)d_in[7];
    const float* w_out = (const float*)d_in[8];
    const float* b_out = (const float*)d_in[9];

    float* out  = (float*)d_out;
    float* kout = out + (size_t)16 * 3 * PPI;          // kernel output region
    u16*   wsu  = (u16*)d_ws;
    float* bout = (float*)((char*)d_ws + BOUT_BYTE);

    prep_kernel<<<(69632 + 28672 + 448 + 255) / 256, 256, 0, stream>>>(
        w_in, rw1, rw2, w_out, b_out, wsu, bout);

    trunk_kernel<<<NPIX / BPX, 1024, 0, stream>>>(
        z, b_in, rb1, rb2, wsu, bout, kout);

    apply_kernel<<<NPIX / BPX, 1024, 0, stream>>>(x, kout, out);
}

// Round 10
// 75.091 us; speedup vs baseline: 1.3707x; 1.2945x over previous
//
#include <hip/hip_runtime.h>
#include <math.h>

#define KS 21
#define K2 441
#define NB 8
#define PPI 4096
#define NPIX 65536
#define STR 72                     // LDS activation row stride (u16), 16B-aligned rows
#define XW 276
#define BPX 256                    // pixels per block

typedef unsigned short u16;
typedef unsigned int u32;
typedef short short8v __attribute__((ext_vector_type(8)));
typedef float f32x4 __attribute__((ext_vector_type(4)));
typedef float f32x16 __attribute__((ext_vector_type(16)));

// ws layout (u16 units): layer frags 17*4096 | wout frags 28672 | bout 448 f32
#define WOUT_OFF 69632
#define BOUT_BYTE 196608

// dynamic-LDS byte offsets (16B aligned)
#define LDS_HBUF  0                // 256*72*2      = 36864
#define LDS_XS    36864            // 33*3*276*2    = 54648 (pad->54656)
#define LDS_BSH   91520            // 448*4         = 1792
#define LDS_SBUF  93312            // 16*32*4       = 2048
#define LDS_OBUF  95360            // 16*3*32*4     = 6144
#define LDS_TOTAL 101504

__device__ __forceinline__ u16 f2bf(float x)
{
    union { float f; u32 u; } c; c.f = x;
    u32 r = c.u + 0x7FFF + ((c.u >> 16) & 1);
    return (u16)(r >> 16);
}
__device__ __forceinline__ float bflo(u32 w)
{ union { u32 u; float f; } c; c.u = w << 16; return c.f; }
__device__ __forceinline__ float bfhi(u32 w)
{ union { u32 u; float f; } c; c.u = w & 0xffff0000u; return c.f; }
__device__ __forceinline__ float u16f(u16 h)
{ union { u32 u; float f; } c; c.u = ((u32)h) << 16; return c.f; }

// XCD-aware bijective swizzle for 256-block grids: XCD x owns 32
// consecutive logical blocks = 8192 consecutive px = 2 whole images.
__device__ __forceinline__ int xcd_swz(int i)
{
    return ((i & 7) << 5) | (i >> 3);
}

// ---------------------------------------------------------------- prep ----
// Layer weights: 16x16x32 B-frag layout (n=lane&15, k=(lane>>4)*8+j, kk*32).
// w_out: 32x32x16 A-frag layout (m=tap=lane&31, k=kk*16+(lane>>5)*8+j),
//   14 tap-tiles x 4 kk. Padded taps (>=441) -> weight 0, bias -100.
__global__ void prep_kernel(const float* __restrict__ w_in,
                            const float* __restrict__ rw1,
                            const float* __restrict__ rw2,
                            const float* __restrict__ w_out,
                            const float* __restrict__ b_out,
                            u16* __restrict__ wsu, float* __restrict__ bout)
{
    int idx = blockIdx.x * 256 + threadIdx.x;
    if (idx < 69632) {
        int u = idx & 4095;
        int j = u & 7, lane = (u >> 3) & 63, frag = (u >> 9) & 7;
        int kk = frag >> 2, nt = frag & 3, layer = idx >> 12;
        int i = kk * 32 + (lane >> 4) * 8 + j;      // K (input ch)
        int o = nt * 16 + (lane & 15);              // N (output ch)
        const float* src;
        if (layer == 0) src = w_in;
        else if (layer & 1) src = rw1 + ((layer - 1) >> 1) * 4096;
        else src = rw2 + ((layer - 2) >> 1) * 4096;
        wsu[idx] = f2bf(src[o * 64 + i]);
    } else if (idx < 69632 + 28672) {
        int u = idx - 69632;
        int j = u & 7, lane = (u >> 3) & 63, t6 = u >> 9;   // 0..55
        int t = t6 % 14, kk = t6 / 14;
        int tap = t * 32 + (lane & 31);
        int i = kk * 16 + (lane >> 5) * 8 + j;
        wsu[idx] = f2bf((tap < K2) ? w_out[tap * 64 + i] : 0.f);
    } else if (idx < 69632 + 28672 + 448) {
        int tap = idx - (69632 + 28672);
        bout[tap] = (tap < K2) ? b_out[tap] : -100.f;
    }
}

// ------------------------------------------------------------- fused -----
__device__ __forceinline__ int reflect256(int v)
{
    v = (v < 0) ? -v : v;
    return (v > 255) ? (510 - v) : v;
}

// Layer step, single in-place buffer (wave-private rows).
template <int MODE>
__device__ __forceinline__ void do_layer(u16* hb, const u16* __restrict__ wb,
                                         const float* __restrict__ bias,
                                         float* hreg, int aoff, int wbase,
                                         int c, int g, int lane)
{
    short8v a0 = *(const short8v*)(hb + aoff);
    short8v a1 = *(const short8v*)(hb + aoff + 32);
#pragma unroll
    for (int nt = 0; nt < 4; ++nt) {
        f32x4 acc = {};
        short8v b0 = *(const short8v*)(wb + ((nt)     * 64 + lane) * 8);
        short8v b1 = *(const short8v*)(wb + ((4 + nt) * 64 + lane) * 8);
        acc = __builtin_amdgcn_mfma_f32_16x16x32_bf16(a0, b0, acc, 0, 0, 0);
        acc = __builtin_amdgcn_mfma_f32_16x16x32_bf16(a1, b1, acc, 0, 0, 0);
        const float bv = bias[nt * 16 + c];
#pragma unroll
        for (int r = 0; r < 4; ++r) {
            float v = acc[r] + bv;
            if (MODE == 1) v = fmaxf(v, 0.f);
            if (MODE == 2) { v += hreg[nt * 4 + r]; hreg[nt * 4 + r] = v; }
            if (MODE == 0) hreg[nt * 4 + r] = v;
            hb[(wbase + g * 4 + r) * STR + nt * 16 + c] = f2bf(v);
        }
    }
}

__launch_bounds__(1024, 1)
__global__ void trunk_kernel(const float* __restrict__ z,
                             const float* __restrict__ x,
                             const float* __restrict__ b_in,
                             const float* __restrict__ rb1,
                             const float* __restrict__ rb2,
                             const u16* __restrict__ wsu,
                             const float* __restrict__ bout,
                             float* __restrict__ out,
                             float* __restrict__ kout)
{
    extern __shared__ __align__(16) char smem[];
    u16*   hbuf = (u16*)(smem + LDS_HBUF);     // [256][STR] in-place acts
    u16*   xs   = (u16*)(smem + LDS_XS);       // [33][3][XW] bf16 x window
    float* bsh  = (float*)(smem + LDS_BSH);    // [448]
    float* sbuf = (float*)(smem + LDS_SBUF);   // [16][32]
    float* obuf = (float*)(smem + LDS_OBUF);   // [16][3][32]

    const int tid = threadIdx.x, lane = tid & 63, wave = tid >> 6;  // 0..15
    const int pix0 = xcd_swz(blockIdx.x) * BPX;
    const int b = pix0 >> 12, rem0 = pix0 & 4095;
    const int hl0 = rem0 >> 6;

    // ---- stage z -> hbuf (bf16); thread (p,g) stages px p, 16 channels ----
    {
        const int p = tid & 255, i0 = (tid >> 8) * 16;
        const float* zp = z + ((size_t)b * 64 + i0) * PPI + rem0 + p;
        u32* dst = (u32*)hbuf + p * (STR / 2) + i0 / 2;
#pragma unroll
        for (int i = 0; i < 16; i += 2) {
            float v0 = zp[(size_t)i * PPI];
            float v1 = zp[(size_t)(i + 1) * PPI];
            dst[i / 2] = (u32)f2bf(v0) | ((u32)f2bf(v1) << 16);
        }
    }
    // ---- stage reflected x: rows hl0*4-10 .. hl0*4+22, cols -10..265 ----
    for (int u = tid; u < 33 * 3 * XW; u += 1024) {
        int t = u / XW;                      // rr*3 + cch
        int j = u - t * XW;
        int rr = t / 3, cch = t - rr * 3;
        int row = reflect256(hl0 * 4 + rr - 10);
        int xcol = reflect256(j - 10);
        xs[u] = f2bf(x[(((size_t)b * 3 + cch) * 256 + row) * 256 + xcol]);
    }
    if (tid < 448) bsh[tid] = bout[tid];
    __syncthreads();

    // ---- 17-layer trunk, wave-private rows [wave*16, wave*16+16) ----
    const int c16 = lane & 15, g4 = lane >> 4;
    const int wbase = wave * 16;
    const int aoff = (wbase + c16) * STR + g4 * 8;
    float hreg[16];

    do_layer<0>(hbuf, wsu, b_in, hreg, aoff, wbase, c16, g4, lane);
#pragma unroll 1
    for (int l = 0; l < NB; ++l) {
        do_layer<1>(hbuf, wsu + (size_t)(1 + 2 * l) * 4096, rb1 + l * 64,
                    hreg, aoff, wbase, c16, g4, lane);
        do_layer<2>(hbuf, wsu + (size_t)(2 + 2 * l) * 4096, rb2 + l * 64,
                    hreg, aoff, wbase, c16, g4, lane);
    }
    __syncthreads();   // pass 1 reads other waves' h rows

    // ---- pass 1 (swapped operands, 32x32x16): D[tap][px], px on lane&31 ----
    const int c32 = lane & 31, hi2 = lane >> 5;
    const int wavepx = (wave >> 1) * 32;       // 0..224
    const int tbase = (wave & 1) * 7;          // 7 of 14 tap-tiles

    short8v bh[4];
#pragma unroll
    for (int kk = 0; kk < 4; ++kk)
        bh[kk] = *(const short8v*)(hbuf + (wavepx + c32) * STR + kk * 16 + hi2 * 8);

    float ssum = 0.f;
    u32 epack[56];
    const u16* wob = wsu + WOUT_OFF;
#pragma unroll
    for (int ti = 0; ti < 7; ++ti) {
        const int t = tbase + ti;
        f32x16 acc = {};
#pragma unroll
        for (int kk = 0; kk < 4; ++kk) {
            short8v aw = *(const short8v*)(wob + ((kk * 14 + t) * 64 + lane) * 8);
            acc = __builtin_amdgcn_mfma_f32_32x32x16_bf16(aw, bh[kk], acc, 0, 0, 0);
        }
#pragma unroll
        for (int rr = 0; rr < 8; ++rr) {
            const int r0 = 2 * rr;
            const int tap0 = t * 32 + (r0 & 3) + 8 * (r0 >> 2) + 4 * hi2;
            float e0 = __expf(acc[r0] + bsh[tap0]);
            float e1 = __expf(acc[r0 + 1] + bsh[tap0 + 1]);
            ssum += e0 + e1;
            epack[ti * 8 + rr] = (u32)f2bf(e0) | ((u32)f2bf(e1) << 16);
        }
    }
    ssum += __shfl_xor(ssum, 32);              // combine hi2 tap-halves
    if (lane < 32) sbuf[wave * 32 + lane] = ssum;
    __syncthreads();
    const float inv_s = 1.f / (ssum + sbuf[(wave ^ 1) * 32 + c32]);

    // ---- pass 2 + fused apply: plain p stores (128B segs) + window FMAs ----
    const int pxl = wavepx + c32;
    const int wl = pxl & 63, hlr = pxl >> 6;
    const int xcb = wl * 4;
    float* kbase = kout + (size_t)b * K2 * PPI + rem0 + pxl;
    float oacc0 = 0.f, oacc1 = 0.f, oacc2 = 0.f;

#pragma unroll
    for (int ti = 0; ti < 7; ++ti) {
        const int t = tbase + ti;
        int tap = t * 32 + 4 * hi2;
        int ky = tap / KS;
        int kx = tap - ky * KS;
#pragma unroll
        for (int rr = 0; rr < 8; ++rr) {
            const u32 ep = epack[ti * 8 + rr];
            float p0 = bflo(ep) * inv_s;
            float p1 = bfhi(ep) * inv_s;
            if (tap < K2) {
                kbase[(size_t)tap * PPI] = p0;
                const u16* xp = xs + ((hlr * 4 + ky) * 3) * XW + xcb + kx;
                oacc0 = fmaf(p0, u16f(xp[0]), oacc0);
                oacc1 = fmaf(p0, u16f(xp[XW]), oacc1);
                oacc2 = fmaf(p0, u16f(xp[2 * XW]), oacc2);
            }
            tap += 1; kx += 1; if (kx >= KS) { kx -= KS; ky += 1; }
            if (tap < K2) {
                kbase[(size_t)tap * PPI] = p1;
                const u16* xp = xs + ((hlr * 4 + ky) * 3) * XW + xcb + kx;
                oacc0 = fmaf(p1, u16f(xp[0]), oacc0);
                oacc1 = fmaf(p1, u16f(xp[XW]), oacc1);
                oacc2 = fmaf(p1, u16f(xp[2 * XW]), oacc2);
            }
            const int d = (rr & 1) ? 5 : 1;    // row-pair walk within C tile
            tap += d; kx += d; if (kx >= KS) { kx -= KS; ky += 1; }
        }
    }

    // ---- out reduction: tap-halves (xor32), then wave-pair via LDS ----
    oacc0 += __shfl_xor(oacc0, 32);
    oacc1 += __shfl_xor(oacc1, 32);
    oacc2 += __shfl_xor(oacc2, 32);
    if (lane < 32) {
        obuf[(wave * 3 + 0) * 32 + lane] = oacc0;
        obuf[(wave * 3 + 1) * 32 + lane] = oacc1;
        obuf[(wave * 3 + 2) * 32 + lane] = oacc2;
    }
    __syncthreads();
    if ((wave & 1) == 0 && lane < 32) {
        const int o = rem0 + wavepx + lane;
#pragma unroll
        for (int cch = 0; cch < 3; ++cch) {
            float v = obuf[(wave * 3 + cch) * 32 + lane] +
                      obuf[((wave + 1) * 3 + cch) * 32 + lane];
            out[((size_t)b * 3 + cch) * PPI + o] = v;
        }
    }
}

// ------------------------------------------------------------ launch -----
extern "C" void kernel_launch(void* const* d_in, const int* in_sizes, int n_in,
                              void* d_out, int out_size, void* d_ws, size_t ws_size,
                              hipStream_t stream)
{
    const float* x     = (const float*)d_in[0];
    const float* z     = (const float*)d_in[1];
    const float* w_in  = (const float*)d_in[2];
    const float* b_in  = (const float*)d_in[3];
    const float* rw1   = (const float*)d_in[4];
    const float* rb1   = (const float*)d_in[5];
    const float* rw2   = (const float*)d_in[6];
    const float* rb2   = (const float*)d_in[7];
    const float* w_out = (const float*)d_in[8];
    const float* b_out = (const float*)d_in[9];

    float* out  = (float*)d_out;
    float* kout = out + (size_t)16 * 3 * PPI;          // kernel output region
    u16*   wsu  = (u16*)d_ws;
    float* bout = (float*)((char*)d_ws + BOUT_BYTE);

    (void)hipFuncSetAttribute((const void*)trunk_kernel,
                              hipFuncAttributeMaxDynamicSharedMemorySize,
                              LDS_TOTAL);

    prep_kernel<<<(69632 + 28672 + 448 + 255) / 256, 256, 0, stream>>>(
        w_in, rw1, rw2, w_out, b_out, wsu, bout);

    trunk_kernel<<<NPIX / BPX, 1024, LDS_TOTAL, stream>>>(
        z, x, b_in, rb1, rb2, wsu, bout, out, kout);
}